// Round 1
// baseline (770.349 us; speedup 1.0000x reference)
//
#include <hip/hip_runtime.h>
#include <cstddef>

#define B_ 8
#define S_ 512
#define D_ 512
#define TS 8
#define NST 64   // S_/TS

// workspace float offsets
#define WS_BASES 0
#define WS_PES   131072
#define WS_BASED 262144
#define WS_PED   393216
#define WS_UD    524288                          // [B][NST][D][32]
#define WS_ZD    (WS_UD + B_*NST*D_*32)          // [B][NST][D]

// output float offsets (h_s, h_d, h_e concatenated)
#define HS_OFF 0
#define HD_OFF 131072
#define HE_OFF 262144

// ---------------- kernel 0: node projections (tiny) ----------------
// base_s = x_s·W_ss + b_ss ; pe_s = x_s·W_es ; base_d = x_d·W_dd + b_dd ; pe_d = x_d·W_ed
__global__ __launch_bounds__(256)
void k0_nodes(const float* __restrict__ x_s, const float* __restrict__ x_d,
              const float* __restrict__ W_ss, const float* __restrict__ b_ss,
              const float* __restrict__ W_dd, const float* __restrict__ b_dd,
              const float* __restrict__ W_es, const float* __restrict__ W_ed,
              float* __restrict__ ws)
{
  int g = blockIdx.x * 256 + threadIdx.x;
  int row = g >> 5, o = g & 31;          // row 0..8191 (supply rows then demand rows)
  bool sup = row < (B_ * S_);
  int r = sup ? row : row - B_ * S_;
  const float* x  = (sup ? x_s : x_d) + r * 32;
  const float* W1 = sup ? W_ss : W_dd;
  const float* W2 = sup ? W_es : W_ed;
  const float* bb = sup ? b_ss : b_dd;
  float xr[32];
#pragma unroll
  for (int k = 0; k < 8; k++)
    *(float4*)&xr[4*k] = *(const float4*)(x + 4*k);
  float acc1 = bb[o], acc2 = 0.f;
#pragma unroll
  for (int e = 0; e < 32; e++) {
    acc1 += xr[e] * W1[o*32 + e];
    acc2 += xr[e] * W2[o*32 + e];
  }
  int ob = sup ? WS_BASES : WS_BASED;
  int op = sup ? WS_PES  : WS_PED;
  ws[ob + r*32 + o] = acc1;
  ws[op + r*32 + o] = acc2;
}

// ---------------- kernel 1: single pass over x_e ----------------
// Block = (b, s-tile of 8). Thread t: s_idx=t>>5, d_off=t&31; pairs (s, d=32i+d_off).
// Produces: h_e (full), h_s (full), u_d/Z_d partials per s-tile into ws.
__global__ __launch_bounds__(256, 2)
void k1_main(const float* __restrict__ x_e,
             const float* __restrict__ a_se_w, const float* __restrict__ a_se_b,
             const float* __restrict__ a_de_w, const float* __restrict__ a_de_b,
             const float* __restrict__ W_se, const float* __restrict__ W_ee,
             const float* __restrict__ b_ee,
             float* __restrict__ ws,
             float* __restrict__ out)
{
  __shared__ float lds_ud[D_ * 33];   // [d][e(32) + z(1)] padded -> bank (d+e)%32
  __shared__ float lds_us[TS * 32];
  __shared__ float lds_zs[TS];

  const int t = threadIdx.x;
  const int s_idx = t >> 5, d_off = t & 31;
  const int st = blockIdx.x, b = blockIdx.y;
  const int s = st * TS + s_idx;

  for (int idx = t; idx < D_ * 33; idx += 256) lds_ud[idx] = 0.f;
  if (t < TS) lds_zs[t] = 0.f;
  __syncthreads();

  const float* xrow  = x_e + ((size_t)(b * S_ + s) * D_) * 32;
  float*       herow = out + HE_OFF + ((size_t)(b * S_ + s) * D_) * 32;
  const float* peS = ws + WS_PES + (b * S_ + s) * 32;
  const float* peD = ws + WS_PED + (size_t)b * D_ * 32;

  float hbase[32];
#pragma unroll
  for (int k = 0; k < 8; k++) {
    float4 v  = *(const float4*)(peS + 4*k);
    float4 be = *(const float4*)(b_ee + 4*k);
    hbase[4*k+0] = v.x + be.x; hbase[4*k+1] = v.y + be.y;
    hbase[4*k+2] = v.z + be.z; hbase[4*k+3] = v.w + be.w;
  }

  float us_acc[32];
#pragma unroll
  for (int e = 0; e < 32; e++) us_acc[e] = 0.f;
  float zs_acc = 0.f;
  const float asb = a_se_b[0], adb = a_de_b[0];

  float4 xb[8];                                   // prefetch buffer (i=0)
#pragma unroll
  for (int k = 0; k < 8; k++)
    xb[k] = *(const float4*)(xrow + d_off*32 + 4*k);

#pragma unroll 1
  for (int i = 0; i < 16; i++) {
    const int d = i*32 + d_off;
    float x[32];
#pragma unroll
    for (int k = 0; k < 8; k++) {
      x[4*k+0] = xb[k].x; x[4*k+1] = xb[k].y;
      x[4*k+2] = xb[k].z; x[4*k+3] = xb[k].w;
    }
    const int dn = (i < 15) ? d + 32 : d;         // prefetch next pair's x
#pragma unroll
    for (int k = 0; k < 8; k++)
      xb[k] = *(const float4*)(xrow + dn*32 + 4*k);

    // logits (a-vectors are uniform -> SGPR operands)
    float ls = asb, ldt = adb;
#pragma unroll
    for (int e = 0; e < 32; e++) {
      ls  += x[e] * a_se_w[e];
      ldt += x[e] * a_de_w[e];
    }
    float es = __expf(ls), ed = __expf(ldt);
    zs_acc += es;
#pragma unroll
    for (int e = 0; e < 32; e++) us_acc[e] += es * x[e];
#pragma unroll
    for (int e = 0; e < 32; e++)
      atomicAdd(&lds_ud[d*33 + e], ed * x[e]);    // ds_add_f32, banks spread
    atomicAdd(&lds_ud[d*33 + 32], ed);            // Z_d partial

    // h_e: x in VGPRs, W_ee rows uniform -> pure v_fma with SGPR src
#pragma unroll
    for (int oq = 0; oq < 8; oq++) {
      float4 pdq = *(const float4*)(peD + d*32 + 4*oq);
      float a0 = 0.f, a1 = 0.f, a2 = 0.f, a3 = 0.f;
#pragma unroll
      for (int e = 0; e < 32; e++) {
        a0 += x[e] * W_ee[(4*oq+0)*32 + e];
        a1 += x[e] * W_ee[(4*oq+1)*32 + e];
        a2 += x[e] * W_ee[(4*oq+2)*32 + e];
        a3 += x[e] * W_ee[(4*oq+3)*32 + e];
      }
      float4 r;
      r.x = a0 + hbase[4*oq+0] + pdq.x;
      r.y = a1 + hbase[4*oq+1] + pdq.y;
      r.z = a2 + hbase[4*oq+2] + pdq.z;
      r.w = a3 + hbase[4*oq+3] + pdq.w;
      *(float4*)(herow + d*32 + 4*oq) = r;
    }
  }

  atomicAdd(&lds_zs[s_idx], zs_acc);
  __syncthreads();

  // flush u_d / Z_d partials for this s-tile (coalesced sweeps)
  float* wud = ws + WS_UD + ((size_t)(b * NST + st) * D_) * 32;
  float* wzd = ws + WS_ZD + (b * NST + st) * D_;
#pragma unroll 1
  for (int sw = 0; sw < 16; sw++) {
    int r = sw * 32 + (t >> 3), g = t & 7;
    *(float4*)(wud + r*32 + g*4) = *(float4*)&lds_ud[r*33 + g*4];
  }
  wzd[t]       = lds_ud[t*33 + 32];
  wzd[t + 256] = lds_ud[(t + 256)*33 + 32];
  __syncthreads();

  // reuse lds_ud as the u_s cross-thread reduction buffer
  float* red = lds_ud;
#pragma unroll
  for (int k = 0; k < 8; k++) {
    float4 v;
    v.x = us_acc[4*k+0]; v.y = us_acc[4*k+1];
    v.z = us_acc[4*k+2]; v.w = us_acc[4*k+3];
    *(float4*)&red[t*33 + 4*k] = v;
  }
  __syncthreads();

  float sum = 0.f;                                 // thread (s_idx, e=d_off)
#pragma unroll 1
  for (int dd = 0; dd < 32; dd++)
    sum += red[(s_idx*32 + dd)*33 + d_off];
  lds_us[s_idx*32 + d_off] = sum / lds_zs[s_idx];  // normalized u_s
  __syncthreads();

  // h_s: o = d_off
  float acc = ws[WS_BASES + (b*S_ + s)*32 + d_off];
#pragma unroll
  for (int e = 0; e < 32; e++)
    acc += W_se[d_off*32 + e] * lds_us[s_idx*32 + e];
  out[HS_OFF + (b*S_ + s)*32 + d_off] = acc;
}

// ---------------- kernel 2: reduce u_d partials + h_d ----------------
__global__ __launch_bounds__(256)
void k2_hd(const float* __restrict__ W_de, const float* __restrict__ ws,
           float* __restrict__ out)
{
  __shared__ float lds_u[8 * 32];
  const int t = threadIdx.x;
  const int r = t >> 5, e = t & 31;
  const int b = blockIdx.x >> 6, dg = blockIdx.x & 63;
  const int d = dg * 8 + r;
  const float* wud = ws + WS_UD;
  const float* wzd = ws + WS_ZD;
  float sum = 0.f, z = 0.f;
#pragma unroll 4
  for (int st = 0; st < NST; st++) {
    sum += wud[((size_t)(b*NST + st) * D_ + d) * 32 + e];
    z   += wzd[(b*NST + st) * D_ + d];
  }
  lds_u[r*32 + e] = sum / z;
  __syncthreads();
  float acc = ws[WS_BASED + (b*D_ + d)*32 + e];    // o = e
#pragma unroll
  for (int ee = 0; ee < 32; ee++)
    acc += W_de[e*32 + ee] * lds_u[r*32 + ee];
  out[HD_OFF + (b*D_ + d)*32 + e] = acc;
}

extern "C" void kernel_launch(void* const* d_in, const int* in_sizes, int n_in,
                              void* d_out, int out_size, void* d_ws, size_t ws_size,
                              hipStream_t stream)
{
  const float* x_s    = (const float*)d_in[0];
  const float* x_d    = (const float*)d_in[1];
  const float* x_e    = (const float*)d_in[2];
  const float* W_ss   = (const float*)d_in[3];
  const float* b_ss   = (const float*)d_in[4];
  const float* W_se   = (const float*)d_in[5];
  const float* a_se_w = (const float*)d_in[6];
  const float* a_se_b = (const float*)d_in[7];
  const float* W_dd   = (const float*)d_in[8];
  const float* b_dd   = (const float*)d_in[9];
  const float* W_de   = (const float*)d_in[10];
  const float* a_de_w = (const float*)d_in[11];
  const float* a_de_b = (const float*)d_in[12];
  const float* W_ee   = (const float*)d_in[13];
  const float* b_ee   = (const float*)d_in[14];
  const float* W_es   = (const float*)d_in[15];
  const float* W_ed   = (const float*)d_in[16];
  float* out = (float*)d_out;
  float* ws  = (float*)d_ws;

  hipLaunchKernelGGL(k0_nodes, dim3(1024), dim3(256), 0, stream,
                     x_s, x_d, W_ss, b_ss, W_dd, b_dd, W_es, W_ed, ws);
  hipLaunchKernelGGL(k1_main, dim3(NST, B_), dim3(256), 0, stream,
                     x_e, a_se_w, a_se_b, a_de_w, a_de_b, W_se, W_ee, b_ee, ws, out);
  hipLaunchKernelGGL(k2_hd, dim3(512), dim3(256), 0, stream, W_de, ws, out);
}